// Round 6
// baseline (143.039 us; speedup 1.0000x reference)
//
#include <hip/hip_runtime.h>
#include <math.h>

#define NB 32
#define CC 512
#define HW 1024
#define NJ 10

typedef float vf4 __attribute__((ext_vector_type(4)));

// Inter-kernel buffers in module device memory; each is fully overwritten
// every invocation before being read — no stale-state dependence.
__device__ float g_gap[NB * CC];
__device__ float g_q[NB * CC];
__device__ float g_invZ[NB];

__device__ __forceinline__ float wave_reduce(float s) {
#pragma unroll
  for (int off = 32; off; off >>= 1) s += __shfl_down(s, off, 64);
  return s;
}

// K1: gap[n,c] = mean over HW. ~11 us at ~97% achievable HBM — rooflined.
// Normal (caching) loads: pulls x into L3 for K3's re-read.
__global__ __launch_bounds__(256) void k_gap(const float* __restrict__ x) {
  int wv = threadIdx.x >> 6, lane = threadIdx.x & 63;
  int r0 = blockIdx.x * 16;
#pragma unroll
  for (int it = 0; it < 4; ++it) {
    int row = r0 + wv * 4 + it;
    const float4* xp = (const float4*)x + (size_t)row * 256;
    float s = 0.f;
#pragma unroll
    for (int k = 0; k < 4; ++k) {
      float4 v = xp[lane + 64 * k];
      s += v.x + v.y + v.z + v.w;
    }
    s = wave_reduce(s);
    if (lane == 0) g_gap[row] = s * (1.0f / 1024.0f);
  }
}

// K2 (tiny): per-n q = sigmoid(conv5(gap)+b) and invZ, computed ONCE instead
// of redundantly in every K3 block. 32 blocks x 512 threads, ~2 us.
__global__ __launch_bounds__(512) void k_q(const float* __restrict__ wq,
                                           const float* __restrict__ bq) {
  int n = blockIdx.x, c = threadIdx.x;
  int wv = c >> 6, lane = c & 63;
  __shared__ float gsh[CC];
  __shared__ float wred[8][NJ];
  const float cj[NJ] = {1.f, 1.f, 0.5f, 1.f / 6.f, 1.f / 24.f, 1.f / 120.f,
                        1.f / 720.f, 1.f / 5040.f, 1.f / 40320.f, 1.f / 362880.f};
  gsh[c] = g_gap[n * CC + c];
  __syncthreads();
  float z = bq[0];
#pragma unroll
  for (int k = 0; k < 5; ++k) {
    int idx = c + k - 2;
    float gv = (idx >= 0 && idx < CC) ? gsh[idx] : 0.f;
    z = fmaf(gv, wq[k], z);
  }
  float qv = 1.f / (1.f + expf(-z));
  g_q[n * CC + c] = qv;
  float pj[NJ];
  float pw = 1.f;
#pragma unroll
  for (int j = 0; j < NJ; ++j) { pj[j] = pw; pw *= qv; }
#pragma unroll
  for (int j = 0; j < NJ; ++j) pj[j] = wave_reduce(pj[j]);
  if (lane == 0) {
#pragma unroll
    for (int j = 0; j < NJ; ++j) wred[wv][j] = pj[j];
  }
  __syncthreads();
  if (c == 0) {
    float Z = 0.f;
#pragma unroll
    for (int j = 0; j < NJ; ++j) {
      float P = 0.f;
#pragma unroll
      for (int w8 = 0; w8 < 8; ++w8) P += wred[w8][j];
      Z = fmaf(cj[j] * P, P, Z);
    }
    g_invZ[n] = 1.f / Z;
  }
}

// K3: moments + output. Block = (n, pblk): 512 ch x 32 positions (8 f4 cols).
// Grid 1024 = 2 scheduling rounds at 2 blocks/CU -> round-2 reads overlap
// round-1 store drains (breaks the system-wide read/compute/store lockstep
// that round-5 showed co-residency alone cannot break).
// Thread (cg,pg): channels cg*8..+7, f4-column pg. xv[8] = 32 VGPR;
// peak live ~95 < 128 cap from __launch_bounds__(512,2) [measured semantics:
// cap = 512/(2*arg); (512,6)->40, (512,4)->64 observed].
// x loads and out stores are nontemporal: last-use data, don't thrash L3.
__global__ __launch_bounds__(512, 2) void k_fused(const float* __restrict__ x,
                                                  float* __restrict__ out) {
  int n = blockIdx.x >> 5, pblk = blockIdx.x & 31;
  int t = threadIdx.x;
  int cg = t >> 3, pg = t & 7;
  int wv = t >> 6, lane = t & 63;

  __shared__ vf4 sred[8][8][NJ + 1];  // [wave][pg][j], +1 f4 pad (44f stride)
  __shared__ vf4 sfin[8][NJ + 1];

  const float cj[NJ] = {1.f, 1.f, 0.5f, 1.f / 6.f, 1.f / 24.f, 1.f / 120.f,
                        1.f / 720.f, 1.f / 5040.f, 1.f / 40320.f, 1.f / 362880.f};

  const vf4* x4 = (const vf4*)x;
  size_t base = (size_t)(n * CC + cg * 8) * 256 + (size_t)pblk * 8 + pg;

  // ---- load x tile (nontemporal: this is x's final read) ----
  vf4 xv[8];
#pragma unroll
  for (int i = 0; i < 8; ++i)
    xv[i] = __builtin_nontemporal_load(&x4[base + (size_t)i * 256]);

  // ---- q for this thread's 8 channels + invZ (precomputed by k_q) ----
  float qv8[8];
  {
    const vf4* q4 = (const vf4*)g_q;
    int qi = (n * CC + cg * 8) >> 2;
    vf4 qa = q4[qi], qb = q4[qi + 1];
    qv8[0] = qa.x; qv8[1] = qa.y; qv8[2] = qa.z; qv8[3] = qa.w;
    qv8[4] = qb.x; qv8[5] = qb.y; qv8[6] = qb.z; qv8[7] = qb.w;
  }
  float invZ = g_invZ[n];

  // ---- phase B: acc_j = sum_i q_i^j * xv[i] over 8 channels ----
  vf4 acc[NJ];
#pragma unroll
  for (int j = 0; j < NJ; ++j) acc[j] = (vf4){0.f, 0.f, 0.f, 0.f};
#pragma unroll
  for (int i = 0; i < 8; ++i) {
    float qc = qv8[i];
    vf4 v = xv[i];
    float w = 1.f;
#pragma unroll
    for (int j = 0; j < NJ; ++j) {
      acc[j] += v * w;
      w *= qc;
    }
  }
  // reduce over the 8 cg-subgroups within this wave (lane bits 3,4,5)
#pragma unroll
  for (int j = 0; j < NJ; ++j) {
#pragma unroll
    for (int m = 8; m <= 32; m <<= 1) {
      acc[j].x += __shfl_xor(acc[j].x, m, 64);
      acc[j].y += __shfl_xor(acc[j].y, m, 64);
      acc[j].z += __shfl_xor(acc[j].z, m, 64);
      acc[j].w += __shfl_xor(acc[j].w, m, 64);
    }
  }
  if (lane < 8) {
#pragma unroll
    for (int j = 0; j < NJ; ++j) sred[wv][lane][j] = acc[j];
  }
  __syncthreads();
  // cross-wave tree: 80 bins (8 pg x 10 j), fold in invZ * 1/j!
  if (t < 80) {
    int pp = t / NJ, j = t - pp * NJ;
    vf4 a = (vf4){0.f, 0.f, 0.f, 0.f};
#pragma unroll
    for (int w8 = 0; w8 < 8; ++w8) a += sred[w8][pp][j];
    sfin[pp][j] = a * (cj[j] * invZ);
  }
  __syncthreads();

  // ---- phase C: out = x * att, x still in registers; nontemporal stores ----
  vf4 sj[NJ];
#pragma unroll
  for (int j = 0; j < NJ; ++j) sj[j] = sfin[pg][j];
  vf4* o4 = (vf4*)out;
#pragma unroll
  for (int i = 0; i < 8; ++i) {
    float qd = qv8[i];
    float w = 1.f;
    vf4 att = (vf4){0.f, 0.f, 0.f, 0.f};
#pragma unroll
    for (int j = 0; j < NJ; ++j) {
      att += sj[j] * w;
      w *= qd;
    }
    __builtin_nontemporal_store(xv[i] * att, &o4[base + (size_t)i * 256]);
  }
}

extern "C" void kernel_launch(void* const* d_in, const int* in_sizes, int n_in,
                              void* d_out, int out_size, void* d_ws, size_t ws_size,
                              hipStream_t stream) {
  const float* x  = (const float*)d_in[0];
  const float* wq = (const float*)d_in[1];
  const float* bq = (const float*)d_in[2];
  float* out = (float*)d_out;
  (void)d_ws; (void)ws_size;  // workspace intentionally unused

  k_gap<<<NB * CC / 16, 256, 0, stream>>>(x);
  k_q<<<NB, 512, 0, stream>>>(wq, bq);
  k_fused<<<NB * 32, 512, 0, stream>>>(x, out);
}

// Round 7
// 127.833 us; speedup vs baseline: 1.1190x; 1.1190x over previous
//
#include <hip/hip_runtime.h>
#include <math.h>

#define NB 32
#define CC 512
#define HW 1024
#define NJ 10

typedef float vf4 __attribute__((ext_vector_type(4)));

// Inter-kernel buffers in module device memory; each is fully overwritten
// every invocation before being read — no stale-state dependence.
__device__ float g_gap[NB * CC];
__device__ float g_q[NB * CC];
__device__ float g_invZ[NB];

__device__ __forceinline__ float wave_reduce(float s) {
#pragma unroll
  for (int off = 32; off; off >>= 1) s += __shfl_down(s, off, 64);
  return s;
}

// K1: gap[n,c] = mean over HW. ~11 us at ~97% achievable HBM — rooflined.
// Normal (caching) loads: pulls x into L3 for K3's re-read.
__global__ __launch_bounds__(256) void k_gap(const float* __restrict__ x) {
  int wv = threadIdx.x >> 6, lane = threadIdx.x & 63;
  int r0 = blockIdx.x * 16;
#pragma unroll
  for (int it = 0; it < 4; ++it) {
    int row = r0 + wv * 4 + it;
    const float4* xp = (const float4*)x + (size_t)row * 256;
    float s = 0.f;
#pragma unroll
    for (int k = 0; k < 4; ++k) {
      float4 v = xp[lane + 64 * k];
      s += v.x + v.y + v.z + v.w;
    }
    s = wave_reduce(s);
    if (lane == 0) g_gap[row] = s * (1.0f / 1024.0f);
  }
}

// K2 (tiny, ~2 us): per-n q = sigmoid(conv5(gap)+b) and invZ, computed ONCE
// instead of redundantly in every K3 block. 32 blocks x 512 threads.
__global__ __launch_bounds__(512) void k_q(const float* __restrict__ wq,
                                           const float* __restrict__ bq) {
  int n = blockIdx.x, c = threadIdx.x;
  int wv = c >> 6, lane = c & 63;
  __shared__ float gsh[CC];
  __shared__ float wred[8][NJ];
  const float cj[NJ] = {1.f, 1.f, 0.5f, 1.f / 6.f, 1.f / 24.f, 1.f / 120.f,
                        1.f / 720.f, 1.f / 5040.f, 1.f / 40320.f, 1.f / 362880.f};
  gsh[c] = g_gap[n * CC + c];
  __syncthreads();
  float z = bq[0];
#pragma unroll
  for (int k = 0; k < 5; ++k) {
    int idx = c + k - 2;
    float gv = (idx >= 0 && idx < CC) ? gsh[idx] : 0.f;
    z = fmaf(gv, wq[k], z);
  }
  float qv = 1.f / (1.f + expf(-z));
  g_q[n * CC + c] = qv;
  float pj[NJ];
  float pw = 1.f;
#pragma unroll
  for (int j = 0; j < NJ; ++j) { pj[j] = pw; pw *= qv; }
#pragma unroll
  for (int j = 0; j < NJ; ++j) pj[j] = wave_reduce(pj[j]);
  if (lane == 0) {
#pragma unroll
    for (int j = 0; j < NJ; ++j) wred[wv][j] = pj[j];
  }
  __syncthreads();
  if (c == 0) {
    float Z = 0.f;
#pragma unroll
    for (int j = 0; j < NJ; ++j) {
      float P = 0.f;
#pragma unroll
      for (int w8 = 0; w8 < 8; ++w8) P += wred[w8][j];
      Z = fmaf(cj[j] * P, P, Z);
    }
    g_invZ[n] = 1.f / Z;
  }
}

// K3: moments + output. ROUND-5 GEOMETRY (proven 25 us clean): 512 blocks
// (n, pblk) of 512 ch x 64 positions; thread (cg,pg) caches
// x[cg*16..+15][pblk*16+pg] in xv[16] (64 VGPR); phase B in two passes of 5
// moments (acc[5] = 20 VGPR). NORMAL loads/stores (round 6 showed nt hints
// stall: 49 us @ 17% VALU / 17% occ). Q phase replaced by g_q/g_invZ reads
// (k_q hoist — the one clean round-6 win). Leash (512,2): measured semantics
// cap = 512/(2*arg) = 128 VGPR, 2 blocks/CU; true peak live ~112 -> no spill.
__global__ __launch_bounds__(512, 2) void k_fused(const float* __restrict__ x,
                                                  float* __restrict__ out) {
  int n = blockIdx.x >> 4, pblk = blockIdx.x & 15;
  int t = threadIdx.x;
  int cg = t >> 4, pg = t & 15;
  int wv = t >> 6, lane = t & 63;

  __shared__ float qs[CC];
  __shared__ vf4 sred[8][16][NJ + 1];  // +1 vf4 pad (stride 44f): no conflict
  __shared__ vf4 sfin[16][NJ + 1];

  const float cj[NJ] = {1.f, 1.f, 0.5f, 1.f / 6.f, 1.f / 24.f, 1.f / 120.f,
                        1.f / 720.f, 1.f / 5040.f, 1.f / 40320.f, 1.f / 362880.f};

  const vf4* x4 = (const vf4*)x;
  size_t base = (size_t)(n * CC + cg * 16) * 256 + (size_t)pblk * 16 + pg;

  // ---- load x tile into registers (read x exactly once in this kernel) ----
  vf4 xv[16];
#pragma unroll
  for (int i = 0; i < 16; ++i) xv[i] = x4[base + (size_t)i * 256];

  // ---- q (per-n, precomputed by k_q) into LDS; invZ broadcast ----
  qs[t] = g_q[n * CC + t];
  float invZ = g_invZ[n];
  __syncthreads();

  // ---- phase B: moments in two passes of 5 (acc[5] = 20 VGPR live) ----
#pragma unroll
  for (int half = 0; half < 2; ++half) {
    vf4 acc[5];
#pragma unroll
    for (int j = 0; j < 5; ++j) acc[j] = (vf4){0.f, 0.f, 0.f, 0.f};
#pragma unroll
    for (int i = 0; i < 16; ++i) {
      float qc = qs[cg * 16 + i];
      float w;
      if (half == 0) {
        w = 1.f;
      } else {
        float q2 = qc * qc;
        float q4 = q2 * q2;
        w = q4 * qc;  // qc^5
      }
      vf4 v = xv[i];
#pragma unroll
      for (int j = 0; j < 5; ++j) {
        acc[j] += v * w;
        w *= qc;
      }
    }
    // reduce over the 4 cg within this wave (lane bits 4,5)
#pragma unroll
    for (int j = 0; j < 5; ++j) {
      acc[j].x += __shfl_xor(acc[j].x, 16, 64);
      acc[j].y += __shfl_xor(acc[j].y, 16, 64);
      acc[j].z += __shfl_xor(acc[j].z, 16, 64);
      acc[j].w += __shfl_xor(acc[j].w, 16, 64);
      acc[j].x += __shfl_xor(acc[j].x, 32, 64);
      acc[j].y += __shfl_xor(acc[j].y, 32, 64);
      acc[j].z += __shfl_xor(acc[j].z, 32, 64);
      acc[j].w += __shfl_xor(acc[j].w, 32, 64);
    }
    if (lane < 16) {
#pragma unroll
      for (int j = 0; j < 5; ++j) sred[wv][lane][half * 5 + j] = acc[j];
    }
  }
  __syncthreads();
  // cross-wave tree: 160 bins (16 pg x 10 j), fold in invZ * 1/j!
  if (t < 160) {
    int pp = t / NJ, j = t - pp * NJ;
    vf4 a = (vf4){0.f, 0.f, 0.f, 0.f};
#pragma unroll
    for (int w8 = 0; w8 < 8; ++w8) a += sred[w8][pp][j];
    sfin[pp][j] = a * (cj[j] * invZ);
  }
  __syncthreads();

  // ---- phase C: out = x * att, x still in registers ----
  vf4 sj[NJ];
#pragma unroll
  for (int j = 0; j < NJ; ++j) sj[j] = sfin[pg][j];
  vf4* o4 = (vf4*)out;
#pragma unroll
  for (int i = 0; i < 16; ++i) {
    float qd = qs[cg * 16 + i];
    float w = 1.f;
    vf4 att = (vf4){0.f, 0.f, 0.f, 0.f};
#pragma unroll
    for (int j = 0; j < NJ; ++j) {
      att += sj[j] * w;
      w *= qd;
    }
    o4[base + (size_t)i * 256] = xv[i] * att;
  }
}

extern "C" void kernel_launch(void* const* d_in, const int* in_sizes, int n_in,
                              void* d_out, int out_size, void* d_ws, size_t ws_size,
                              hipStream_t stream) {
  const float* x  = (const float*)d_in[0];
  const float* wq = (const float*)d_in[1];
  const float* bq = (const float*)d_in[2];
  float* out = (float*)d_out;
  (void)d_ws; (void)ws_size;  // workspace intentionally unused

  k_gap<<<NB * CC / 16, 256, 0, stream>>>(x);
  k_q<<<NB, 512, 0, stream>>>(wq, bq);
  k_fused<<<NB * 16, 512, 0, stream>>>(x, out);
}

// Round 8
// 126.685 us; speedup vs baseline: 1.1291x; 1.0091x over previous
//
#include <hip/hip_runtime.h>
#include <math.h>

#define NB 32
#define CC 512
#define HW 1024
#define NJ 10

typedef float vf4 __attribute__((ext_vector_type(4)));

// Inter-kernel buffers in module device memory; each is fully overwritten
// every invocation before being read — no stale-state dependence.
__device__ float g_gap[NB * CC];
__device__ float g_q[NB * CC];
__device__ float g_invZ[NB];

__device__ __forceinline__ float wave_reduce(float s) {
#pragma unroll
  for (int off = 32; off; off >>= 1) s += __shfl_down(s, off, 64);
  return s;
}

// K1: gap[n,c] = mean over HW. ~11 us at ~97% achievable HBM — rooflined.
// Normal (caching) loads: pulls x into L3 for K3's re-read.
__global__ __launch_bounds__(256) void k_gap(const float* __restrict__ x) {
  int wv = threadIdx.x >> 6, lane = threadIdx.x & 63;
  int r0 = blockIdx.x * 16;
#pragma unroll
  for (int it = 0; it < 4; ++it) {
    int row = r0 + wv * 4 + it;
    const float4* xp = (const float4*)x + (size_t)row * 256;
    float s = 0.f;
#pragma unroll
    for (int k = 0; k < 4; ++k) {
      float4 v = xp[lane + 64 * k];
      s += v.x + v.y + v.z + v.w;
    }
    s = wave_reduce(s);
    if (lane == 0) g_gap[row] = s * (1.0f / 1024.0f);
  }
}

// K2 (tiny, ~2 us): per-n q = sigmoid(conv5(gap)+b) and invZ, computed ONCE
// instead of redundantly in every K3 block. 32 blocks x 512 threads.
__global__ __launch_bounds__(512) void k_q(const float* __restrict__ wq,
                                           const float* __restrict__ bq) {
  int n = blockIdx.x, c = threadIdx.x;
  int wv = c >> 6, lane = c & 63;
  __shared__ float gsh[CC];
  __shared__ float wred[8][NJ];
  const float cj[NJ] = {1.f, 1.f, 0.5f, 1.f / 6.f, 1.f / 24.f, 1.f / 120.f,
                        1.f / 720.f, 1.f / 5040.f, 1.f / 40320.f, 1.f / 362880.f};
  gsh[c] = g_gap[n * CC + c];
  __syncthreads();
  float z = bq[0];
#pragma unroll
  for (int k = 0; k < 5; ++k) {
    int idx = c + k - 2;
    float gv = (idx >= 0 && idx < CC) ? gsh[idx] : 0.f;
    z = fmaf(gv, wq[k], z);
  }
  float qv = 1.f / (1.f + expf(-z));
  g_q[n * CC + c] = qv;
  float pj[NJ];
  float pw = 1.f;
#pragma unroll
  for (int j = 0; j < NJ; ++j) { pj[j] = pw; pw *= qv; }
#pragma unroll
  for (int j = 0; j < NJ; ++j) pj[j] = wave_reduce(pj[j]);
  if (lane == 0) {
#pragma unroll
    for (int j = 0; j < NJ; ++j) wred[wv][j] = pj[j];
  }
  __syncthreads();
  if (c == 0) {
    float Z = 0.f;
#pragma unroll
    for (int j = 0; j < NJ; ++j) {
      float P = 0.f;
#pragma unroll
      for (int w8 = 0; w8 < 8; ++w8) P += wred[w8][j];
      Z = fmaf(cj[j] * P, P, Z);
    }
    g_invZ[n] = 1.f / Z;
  }
}

// K3: moments + output. Round-7 structure (measured ~18 us, 92% of its HBM
// floor) with ONE change: phase-C stores are NONTEMPORAL. Mechanism: the
// 70 MB output stream was allocating L3 lines and evicting x (round-6/7
// FETCH showed ~34 MB of the x re-read missing L3 even though x fits);
// nt stores mark out evict-first so x stays L3-resident and the re-read
// hits. Loads stay NORMAL (round 6 proved nt LOADS stall: they bypass the
// very caches that hold x). Leash (512,2): measured semantics cap =
// 512/(2*arg) = 128 VGPR, 2 blocks/CU; true peak live ~112 -> no spill.
__global__ __launch_bounds__(512, 2) void k_fused(const float* __restrict__ x,
                                                  float* __restrict__ out) {
  int n = blockIdx.x >> 4, pblk = blockIdx.x & 15;
  int t = threadIdx.x;
  int cg = t >> 4, pg = t & 15;
  int wv = t >> 6, lane = t & 63;

  __shared__ float qs[CC];
  __shared__ vf4 sred[8][16][NJ + 1];  // +1 vf4 pad (stride 44f): no conflict
  __shared__ vf4 sfin[16][NJ + 1];

  const float cj[NJ] = {1.f, 1.f, 0.5f, 1.f / 6.f, 1.f / 24.f, 1.f / 120.f,
                        1.f / 720.f, 1.f / 5040.f, 1.f / 40320.f, 1.f / 362880.f};

  const vf4* x4 = (const vf4*)x;
  size_t base = (size_t)(n * CC + cg * 16) * 256 + (size_t)pblk * 16 + pg;

  // ---- load x tile into registers (read x exactly once in this kernel) ----
  vf4 xv[16];
#pragma unroll
  for (int i = 0; i < 16; ++i) xv[i] = x4[base + (size_t)i * 256];

  // ---- q (per-n, precomputed by k_q) into LDS; invZ broadcast ----
  qs[t] = g_q[n * CC + t];
  float invZ = g_invZ[n];
  __syncthreads();

  // ---- phase B: moments in two passes of 5 (acc[5] = 20 VGPR live) ----
#pragma unroll
  for (int half = 0; half < 2; ++half) {
    vf4 acc[5];
#pragma unroll
    for (int j = 0; j < 5; ++j) acc[j] = (vf4){0.f, 0.f, 0.f, 0.f};
#pragma unroll
    for (int i = 0; i < 16; ++i) {
      float qc = qs[cg * 16 + i];
      float w;
      if (half == 0) {
        w = 1.f;
      } else {
        float q2 = qc * qc;
        float q4 = q2 * q2;
        w = q4 * qc;  // qc^5
      }
      vf4 v = xv[i];
#pragma unroll
      for (int j = 0; j < 5; ++j) {
        acc[j] += v * w;
        w *= qc;
      }
    }
    // reduce over the 4 cg within this wave (lane bits 4,5)
#pragma unroll
    for (int j = 0; j < 5; ++j) {
      acc[j].x += __shfl_xor(acc[j].x, 16, 64);
      acc[j].y += __shfl_xor(acc[j].y, 16, 64);
      acc[j].z += __shfl_xor(acc[j].z, 16, 64);
      acc[j].w += __shfl_xor(acc[j].w, 16, 64);
      acc[j].x += __shfl_xor(acc[j].x, 32, 64);
      acc[j].y += __shfl_xor(acc[j].y, 32, 64);
      acc[j].z += __shfl_xor(acc[j].z, 32, 64);
      acc[j].w += __shfl_xor(acc[j].w, 32, 64);
    }
    if (lane < 16) {
#pragma unroll
      for (int j = 0; j < 5; ++j) sred[wv][lane][half * 5 + j] = acc[j];
    }
  }
  __syncthreads();
  // cross-wave tree: 160 bins (16 pg x 10 j), fold in invZ * 1/j!
  if (t < 160) {
    int pp = t / NJ, j = t - pp * NJ;
    vf4 a = (vf4){0.f, 0.f, 0.f, 0.f};
#pragma unroll
    for (int w8 = 0; w8 < 8; ++w8) a += sred[w8][pp][j];
    sfin[pp][j] = a * (cj[j] * invZ);
  }
  __syncthreads();

  // ---- phase C: out = x * att; NONTEMPORAL stores (don't evict x from L3) ----
  vf4 sj[NJ];
#pragma unroll
  for (int j = 0; j < NJ; ++j) sj[j] = sfin[pg][j];
  vf4* o4 = (vf4*)out;
#pragma unroll
  for (int i = 0; i < 16; ++i) {
    float qd = qs[cg * 16 + i];
    float w = 1.f;
    vf4 att = (vf4){0.f, 0.f, 0.f, 0.f};
#pragma unroll
    for (int j = 0; j < NJ; ++j) {
      att += sj[j] * w;
      w *= qd;
    }
    __builtin_nontemporal_store(xv[i] * att, &o4[base + (size_t)i * 256]);
  }
}

extern "C" void kernel_launch(void* const* d_in, const int* in_sizes, int n_in,
                              void* d_out, int out_size, void* d_ws, size_t ws_size,
                              hipStream_t stream) {
  const float* x  = (const float*)d_in[0];
  const float* wq = (const float*)d_in[1];
  const float* bq = (const float*)d_in[2];
  float* out = (float*)d_out;
  (void)d_ws; (void)ws_size;  // workspace intentionally unused

  k_gap<<<NB * CC / 16, 256, 0, stream>>>(x);
  k_q<<<NB, 512, 0, stream>>>(wq, bq);
  k_fused<<<NB * 16, 512, 0, stream>>>(x, out);
}